// Round 7
// baseline (239.145 us; speedup 1.0000x reference)
//
#include <hip/hip_runtime.h>
#include <hip/hip_bf16.h>

typedef __bf16 bf16_t;
typedef __bf16 bf16x8 __attribute__((ext_vector_type(8)));
typedef float f32x4 __attribute__((ext_vector_type(4)));

// ---------------------------------------------------------------------------
// fp32 src[R][C] -> bf16 dst[C][R]
// ---------------------------------------------------------------------------
__global__ __launch_bounds__(256) void transpose_cast_kernel(
    const float* __restrict__ src, bf16_t* __restrict__ dst, int R, int C)
{
    __shared__ float tile[32][33];
    const int bx = blockIdx.x;  // C/32
    const int by = blockIdx.y;  // R/32
    const int t  = threadIdx.x;
    const int i0 = t >> 5;      // 0..7
    const int j  = t & 31;
#pragma unroll
    for (int p = 0; p < 4; ++p) {
        int i = i0 + p * 8;
        tile[i][j] = src[(long)(by * 32 + i) * C + bx * 32 + j];
    }
    __syncthreads();
#pragma unroll
    for (int p = 0; p < 4; ++p) {
        int i = i0 + p * 8;
        dst[(long)(bx * 32 + i) * R + by * 32 + j] = (bf16_t)tile[j][i];
    }
}

// ---------------------------------------------------------------------------
// fp32 -> bf16 elementwise (x pre-convert; n % 2048 == 0)
// ---------------------------------------------------------------------------
__global__ __launch_bounds__(256) void cast_bf16_kernel(
    const float* __restrict__ src, bf16_t* __restrict__ dst, long n)
{
    const long i = ((long)blockIdx.x * 256 + threadIdx.x) * 8;
    if (i < n) {
        f32x4 a = *(const f32x4*)(src + i);
        f32x4 b = *(const f32x4*)(src + i + 4);
        bf16x8 o;
        o[0] = (bf16_t)a[0]; o[1] = (bf16_t)a[1];
        o[2] = (bf16_t)a[2]; o[3] = (bf16_t)a[3];
        o[4] = (bf16_t)b[0]; o[5] = (bf16_t)b[1];
        o[6] = (bf16_t)b[2]; o[7] = (bf16_t)b[3];
        *(bf16x8*)(dst + i) = o;
    }
}

// ---------------------------------------------------------------------------
// QKV + window attention: one block per (window-PAIR, head), 2048 blocks,
// 256 thr, 48 KB LDS -> 3 blocks/CU. XCD swizzle keeps a pair's 8 head-blocks
// + 32 pairs on one XCD (bf16 x working set 4 MB = L2-resident).
// GEMM phase: M=128 (2 windows x 64 tokens), N=192 (Q|K|V x 64), K=512,
// waves 2x2 (wm = window!), acc 4x6. Scatter -> per-window Q/K/VT tiles.
// Attention: wave = (window wv=wave>>1, half=wave&1), 32 query rows/wave;
// P overwrites the wave's own Q rows (wave-private). O -> ao in proj layout:
//   ao row m = b*4096 + h*512 + n*8 + (w>>3), channel c = (w&7)*64 + d.
// ---------------------------------------------------------------------------
__global__ __launch_bounds__(256, 3) void qkv_attn_kernel(
    const bf16_t* __restrict__ xb,    // [65536][512] bf16
    const bf16_t* __restrict__ wT,    // [1536][512]  (= w_qkv^T, bf16)
    bf16_t* __restrict__ ao)          // [32768][512] bf16, proj layout
{
    __shared__ bf16_t lds[24576];     // 49152 B
    bf16_t* const lX = lds;           // GEMM: [128][64]
    bf16_t* const lW = lds + 8192;    // GEMM: [192][64]
    // Attention tiles (per window wv): base wv*12288: Q(+0) K(+4096) VT(+8192)

    const int id   = blockIdx.x;      // 0..2047
    const int xcd  = id & 7;
    const int s    = id >> 3;         // 0..255
    const int pair = xcd * 32 + (s >> 3);  // 0..255 (windows 2p, 2p+1)
    const int h    = s & 7;

    const int t    = threadIdx.x;
    const int wave = t >> 6;
    const int lane = t & 63;
    const int lr   = lane & 15;
    const int q    = lane >> 4;
    const int wm   = wave >> 1;       // row-half of M=128 == window index
    const int wn   = wave & 1;        // col-half (96 cols each)

    const bf16_t* xw = xb + (long)pair * 128 * 512;

    const float scale = 0.125f;       // dh^-0.5

    // ---- QKV GEMM: M=128, N=192, K=512 ----
    f32x4 acc[4][6];
#pragma unroll
    for (int i = 0; i < 4; ++i)
#pragma unroll
        for (int j = 0; j < 6; ++j) acc[i][j] = (f32x4)0.0f;

    for (int kc = 0; kc < 8; ++kc) {
        const int k0 = kc * 64;
        // stage x [128][64]: 1024 vec8, 4/thread
#pragma unroll
        for (int p = 0; p < 4; ++p) {
            const int v = t + p * 256;
            const int r = v >> 3, c = (v & 7) * 8;
            *(bf16x8*)&lX[r * 64 + c] = *(const bf16x8*)(xw + (long)r * 512 + k0 + c);
        }
        // stage wT [192][64]: rows g*512 + h*64 + i; 1536 vec8, 6/thread
#pragma unroll
        for (int p = 0; p < 6; ++p) {
            const int v = t + p * 256;
            const int nr = v >> 3, c = (v & 7) * 8;
            const int g = nr >> 6, i = nr & 63;
            *(bf16x8*)&lW[nr * 64 + c] =
                *(const bf16x8*)(wT + (long)(g * 512 + h * 64 + i) * 512 + k0 + c);
        }
        __syncthreads();
#pragma unroll
        for (int ks = 0; ks < 64; ks += 32) {
            bf16x8 af[4], bf[6];
#pragma unroll
            for (int i = 0; i < 4; ++i)
                af[i] = *(const bf16x8*)&lX[(wm * 64 + i * 16 + lr) * 64 + ks + q * 8];
#pragma unroll
            for (int j = 0; j < 6; ++j)
                bf[j] = *(const bf16x8*)&lW[(wn * 96 + j * 16 + lr) * 64 + ks + q * 8];
#pragma unroll
            for (int i = 0; i < 4; ++i)
#pragma unroll
                for (int j = 0; j < 6; ++j)
                    acc[i][j] = __builtin_amdgcn_mfma_f32_16x16x32_bf16(
                        af[i], bf[j], acc[i][j], 0, 0, 0);
        }
        __syncthreads();
    }

    // ---- scatter acc -> Q/K/VT tiles (window = wm), stride 64 ----
    // col = wn*96 + j*16 + lr: [0,64)=Q, [64,128)=K, [128,192)=V(->VT)
    {
        bf16_t* const tQ  = &lds[wm * 12288];
        bf16_t* const tK  = tQ + 4096;
        bf16_t* const tVT = tQ + 8192;
#pragma unroll
        for (int i = 0; i < 4; ++i)
#pragma unroll
            for (int j = 0; j < 6; ++j) {
                const int col = wn * 96 + j * 16 + lr;
#pragma unroll
                for (int reg = 0; reg < 4; ++reg) {
                    const int wr = i * 16 + q * 4 + reg;
                    const bf16_t val = (bf16_t)acc[i][j][reg];
                    if (col < 64)       tQ[wr * 64 + col];
                    if (col < 64)       tQ[wr * 64 + col] = val;
                    else if (col < 128) tK[wr * 64 + (col - 64)] = val;
                    else                tVT[(col - 128) * 64 + wr] = val;
                }
            }
    }
    __syncthreads();

    // ---- attention: wave -> (window wv, row-half) ----
    const int wv   = wave >> 1;
    const int half = wave & 1;
    bf16_t* const tQ  = &lds[wv * 12288];   // becomes P after softmax
    bf16_t* const tK  = tQ + 4096;
    bf16_t* const tVT = tQ + 8192;

    // S = Q K^T : rows half*32 .. +31 (2 row-tiles), all 64 k-cols (4 tiles)
    f32x4 sA[2][4];
#pragma unroll
    for (int rt = 0; rt < 2; ++rt)
#pragma unroll
        for (int j = 0; j < 4; ++j) sA[rt][j] = (f32x4)0.0f;
#pragma unroll
    for (int ks = 0; ks < 64; ks += 32) {
        bf16x8 aq[2], bk[4];
#pragma unroll
        for (int rt = 0; rt < 2; ++rt)
            aq[rt] = *(const bf16x8*)&tQ[(half * 32 + rt * 16 + lr) * 64 + ks + q * 8];
#pragma unroll
        for (int j = 0; j < 4; ++j)
            bk[j] = *(const bf16x8*)&tK[(j * 16 + lr) * 64 + ks + q * 8];
#pragma unroll
        for (int rt = 0; rt < 2; ++rt)
#pragma unroll
            for (int j = 0; j < 4; ++j)
                sA[rt][j] = __builtin_amdgcn_mfma_f32_16x16x32_bf16(
                    aq[rt], bk[j], sA[rt][j], 0, 0, 0);
    }

    // softmax rows (wave-private): row = half*32 + rt*16 + q*4 + reg
#pragma unroll
    for (int rt = 0; rt < 2; ++rt)
#pragma unroll
        for (int reg = 0; reg < 4; ++reg) {
            float m = fmaxf(fmaxf(sA[rt][0][reg], sA[rt][1][reg]),
                            fmaxf(sA[rt][2][reg], sA[rt][3][reg]));
#pragma unroll
            for (int d = 1; d < 16; d <<= 1) m = fmaxf(m, __shfl_xor(m, d));
            float p[4];
            float sum = 0.0f;
#pragma unroll
            for (int j = 0; j < 4; ++j) {
                p[j] = __expf((sA[rt][j][reg] - m) * scale);
                sum += p[j];
            }
#pragma unroll
            for (int d = 1; d < 16; d <<= 1) sum += __shfl_xor(sum, d);
            const float inv = 1.0f / sum;
            const int row = half * 32 + rt * 16 + q * 4 + reg;
#pragma unroll
            for (int j = 0; j < 4; ++j)
                tQ[row * 64 + j * 16 + lr] = (bf16_t)(p[j] * inv);  // P over Q
        }

    // O = P V  (A from P rows, B from VT rows)
    f32x4 o[2][4];
#pragma unroll
    for (int rt = 0; rt < 2; ++rt)
#pragma unroll
        for (int d4 = 0; d4 < 4; ++d4) o[rt][d4] = (f32x4)0.0f;
#pragma unroll
    for (int ks = 0; ks < 64; ks += 32) {
        bf16x8 ap[2], bv[4];
#pragma unroll
        for (int rt = 0; rt < 2; ++rt)
            ap[rt] = *(const bf16x8*)&tQ[(half * 32 + rt * 16 + lr) * 64 + ks + q * 8];
#pragma unroll
        for (int d4 = 0; d4 < 4; ++d4)
            bv[d4] = *(const bf16x8*)&tVT[(d4 * 16 + lr) * 64 + ks + q * 8];
#pragma unroll
        for (int rt = 0; rt < 2; ++rt)
#pragma unroll
            for (int d4 = 0; d4 < 4; ++d4)
                o[rt][d4] = __builtin_amdgcn_mfma_f32_16x16x32_bf16(
                    ap[rt], bv[d4], o[rt][d4], 0, 0, 0);
    }

    // ---- write O to ao in proj-matrix coordinates ----
    const int wid = pair * 2 + wv;
    const int bb  = wid >> 6;
    const int nw  = wid & 63;
    bf16_t* aop = ao + ((long)bb * 4096 + (long)h * 512 + nw * 8) * 512;
#pragma unroll
    for (int rt = 0; rt < 2; ++rt)
#pragma unroll
        for (int d4 = 0; d4 < 4; ++d4)
#pragma unroll
            for (int reg = 0; reg < 4; ++reg) {
                const int wr = half * 32 + rt * 16 + q * 4 + reg;
                aop[(long)(wr >> 3) * 512 + (wr & 7) * 64 + d4 * 16 + lr] =
                    (bf16_t)o[rt][d4][reg];
            }
}

// ---------------------------------------------------------------------------
// out[M,N] = ao[M,K] @ pT[N,K]^T + bias, bf16 in / fp32 out, fp32 accumulate.
// 128x128 tile, BK=64, 4 waves (2x2), 4x4 MFMA 16x16x32 per wave.
// XCD swizzle: same-bm group on one XCD (per-XCD A working set ~4 MB = L2).
// ---------------------------------------------------------------------------
#define LDP 72

__global__ __launch_bounds__(256) void gemm2_kernel(
    const bf16_t* __restrict__ A,    // [M,K] = ao
    const bf16_t* __restrict__ Bt,   // [N,K] = pT
    const float*  __restrict__ bias, // [N]
    float* __restrict__ C,           // [M,N]
    int M, int N, int K)
{
    __shared__ bf16_t lA[128 * LDP];
    __shared__ bf16_t lB[128 * LDP];

    const int tid  = threadIdx.x;
    const int wave = tid >> 6;
    const int lane = tid & 63;
    const int wm   = wave >> 1;
    const int wn   = wave & 1;
    const int lr   = lane & 15;
    const int q    = lane >> 4;

    const int id  = blockIdx.x;       // 0..1023
    const int xcd = id & 7;
    const int s   = id >> 3;          // 0..127
    const int bm  = xcd * 32 + (s >> 2);
    const int bn  = s & 3;

    const long arow0 = (long)bm * 128;
    const long brow0 = (long)bn * 128;

    f32x4 acc[4][4];
#pragma unroll
    for (int i = 0; i < 4; ++i)
#pragma unroll
        for (int j = 0; j < 4; ++j) acc[i][j] = (f32x4)0.0f;

    const int srow = tid >> 3;        // 0..31
    const int scol = (tid & 7) * 8;   // 0..56

    const int nk = K / 64;
    for (int kt = 0; kt < nk; ++kt) {
        const bf16_t* Ag = A + arow0 * K + kt * 64;
        const bf16_t* Bg = Bt + brow0 * K + kt * 64;
        bf16x8 av[4], bv[4];
#pragma unroll
        for (int p = 0; p < 4; ++p) {
            const int r = srow + p * 32;
            av[p] = *(const bf16x8*)(Ag + (long)r * K + scol);
            bv[p] = *(const bf16x8*)(Bg + (long)r * K + scol);
        }
#pragma unroll
        for (int p = 0; p < 4; ++p) {
            const int r = srow + p * 32;
            *(bf16x8*)&lA[r * LDP + scol] = av[p];
            *(bf16x8*)&lB[r * LDP + scol] = bv[p];
        }
        __syncthreads();
#pragma unroll
        for (int ks = 0; ks < 64; ks += 32) {
            bf16x8 af[4], bf[4];
#pragma unroll
            for (int i = 0; i < 4; ++i)
                af[i] = *(const bf16x8*)&lA[(wm * 64 + i * 16 + lr) * LDP + ks + q * 8];
#pragma unroll
            for (int j = 0; j < 4; ++j)
                bf[j] = *(const bf16x8*)&lB[(wn * 64 + j * 16 + lr) * LDP + ks + q * 8];
#pragma unroll
            for (int i = 0; i < 4; ++i)
#pragma unroll
                for (int j = 0; j < 4; ++j)
                    acc[i][j] = __builtin_amdgcn_mfma_f32_16x16x32_bf16(
                        af[i], bf[j], acc[i][j], 0, 0, 0);
        }
        __syncthreads();
    }

#pragma unroll
    for (int i = 0; i < 4; ++i) {
        const long r = arow0 + wm * 64 + i * 16 + q * 4;
#pragma unroll
        for (int j = 0; j < 4; ++j) {
            const long c = brow0 + wn * 64 + j * 16 + lr;
            const float bv2 = bias[c];
#pragma unroll
            for (int reg = 0; reg < 4; ++reg) {
                C[(r + reg) * N + c] = acc[i][j][reg] + bv2;
            }
        }
    }
}

// ---------------------------------------------------------------------------
extern "C" void kernel_launch(void* const* d_in, const int* in_sizes, int n_in,
                              void* d_out, int out_size, void* d_ws, size_t ws_size,
                              hipStream_t stream)
{
    (void)in_sizes; (void)n_in; (void)out_size; (void)ws_size;
    const float* x     = (const float*)d_in[0];  // [8,64,64,512] fp32
    const float* wqkv  = (const float*)d_in[1];  // [512,1536] fp32
    const float* wproj = (const float*)d_in[2];  // [512,512] fp32
    const float* bproj = (const float*)d_in[3];  // [512] fp32
    float* out = (float*)d_out;                  // [8,64,64,512] fp32

    // workspace: wT 1.5 + pT 0.5 + ao 32 + xb 32 = ~66 MB
    bf16_t* wT = (bf16_t*)d_ws;                  // [1536][512]
    bf16_t* pT = wT + (size_t)1536 * 512;        // [512][512]
    bf16_t* ao = pT + (size_t)512 * 512;         // [32768][512] proj layout
    bf16_t* xb = ao + (size_t)32768 * 512;       // [65536][512] bf16 x

    transpose_cast_kernel<<<dim3(48, 16), 256, 0, stream>>>(wqkv, wT, 512, 1536);
    transpose_cast_kernel<<<dim3(16, 16), 256, 0, stream>>>(wproj, pT, 512, 512);

    const long nx = (long)16777216;              // 8*64*64*512
    cast_bf16_kernel<<<(int)(nx / 2048), 256, 0, stream>>>(x, xb, nx);

    qkv_attn_kernel<<<2048, 256, 0, stream>>>(xb, wT, ao);

    gemm2_kernel<<<1024, 256, 0, stream>>>(
        ao, pT, bproj, out, 32768, 512, 512);
}